// Round 1
// baseline (2203.266 us; speedup 1.0000x reference)
//
#include <hip/hip_runtime.h>

#define N_ROWS 32768   // BS*SEQ = 32*1024
#define N_CODES 8192
#define DIM 256
#define BM 64          // rows per block
#define BN 64          // codes per tile
#define BK 32          // D chunk
#define XS_LD 68       // padded leading dim (multiple of 4 floats -> 16B aligned rows)
#define CS_LD 68

// ---------------- c_sq: one wave per code ----------------
__global__ void csq_kernel(const float* __restrict__ C, float* __restrict__ csq) {
    int gtid = blockIdx.x * blockDim.x + threadIdx.x;
    int wave = gtid >> 6;          // 0..8191
    int lane = threadIdx.x & 63;
    float4 v = reinterpret_cast<const float4*>(C + (size_t)wave * DIM)[lane];
    float s = v.x * v.x + v.y * v.y + v.z * v.z + v.w * v.w;
    #pragma unroll
    for (int m = 32; m; m >>= 1) s += __shfl_xor(s, m);
    if (lane == 0) csq[wave] = s;
}

// ---------------- argmin over codes ----------------
__global__ __launch_bounds__(256, 2) void argmin_kernel(
        const float* __restrict__ X, const float* __restrict__ C,
        const float* __restrict__ csq, int* __restrict__ outidx) {
    __shared__ __align__(16) float Xs[DIM][XS_LD];   // 256*68*4 = 69632 B, Xs[d][row]
    __shared__ __align__(16) float Cs[BK][CS_LD];    // 32*68*4  =  8704 B, Cs[d][code]

    const int tid = threadIdx.x;
    const int tx = tid & 15;       // code group (4 codes)
    const int ty = tid >> 4;       // row group  (4 rows)
    const int rowbase = blockIdx.x * BM;

    // ---- stage X tile: 64 rows x 256 d, transposed into Xs[d][row]
    {
        const float4* Xg = reinterpret_cast<const float4*>(X + (size_t)rowbase * DIM);
        #pragma unroll
        for (int i = 0; i < 16; ++i) {
            int c = tid + i * 256;        // 0..4095 float4 chunks
            int row = c >> 6;
            int d4  = c & 63;
            float4 v = Xg[c];
            Xs[4 * d4 + 0][row] = v.x;
            Xs[4 * d4 + 1][row] = v.y;
            Xs[4 * d4 + 2][row] = v.z;
            Xs[4 * d4 + 3][row] = v.w;
        }
    }
    __syncthreads();

    float best[4];
    int   bidx[4];
    #pragma unroll
    for (int i = 0; i < 4; ++i) { best[i] = 3.4e38f; bidx[i] = 0; }

    for (int ct = 0; ct < N_CODES / BN; ++ct) {      // 128 code tiles
        const int code0 = ct * BN;
        float acc[4][4];
        #pragma unroll
        for (int i = 0; i < 4; ++i)
            #pragma unroll
            for (int j = 0; j < 4; ++j) acc[i][j] = 0.0f;

        for (int dc = 0; dc < DIM / BK; ++dc) {      // 8 D-chunks
            __syncthreads();   // previous Cs readers done
            // stage Cs[32][64]: 64 codes x 32 d, 2 float4 per thread
            #pragma unroll
            for (int i = 0; i < 2; ++i) {
                int c = tid + i * 256;               // 0..511
                int code = c >> 3;                   // 0..63
                int dq = c & 7;                      // float4 within the 32-d chunk
                float4 v = reinterpret_cast<const float4*>(
                    C + (size_t)(code0 + code) * DIM + dc * BK)[dq];
                Cs[4 * dq + 0][code] = v.x;
                Cs[4 * dq + 1][code] = v.y;
                Cs[4 * dq + 2][code] = v.z;
                Cs[4 * dq + 3][code] = v.w;
            }
            __syncthreads();

            #pragma unroll
            for (int k = 0; k < BK; ++k) {
                float4 a = *reinterpret_cast<const float4*>(&Xs[dc * BK + k][ty * 4]);
                float4 b = *reinterpret_cast<const float4*>(&Cs[k][tx * 4]);
                float av[4] = {a.x, a.y, a.z, a.w};
                float bv[4] = {b.x, b.y, b.z, b.w};
                #pragma unroll
                for (int i = 0; i < 4; ++i)
                    #pragma unroll
                    for (int j = 0; j < 4; ++j)
                        acc[i][j] = fmaf(av[i], bv[j], acc[i][j]);
            }
        }

        // dist = csq[code] - 2*dot ; running argmin (strict < keeps lowest index)
        #pragma unroll
        for (int j = 0; j < 4; ++j) {
            int code = code0 + tx * 4 + j;
            float cs = csq[code];
            #pragma unroll
            for (int i = 0; i < 4; ++i) {
                float d = fmaf(-2.0f, acc[i][j], cs);
                if (d < best[i]) { best[i] = d; bidx[i] = code; }
            }
        }
    }

    // reduce across the 16 tx-lanes sharing each row group (lanes are contiguous)
    #pragma unroll
    for (int m = 1; m < 16; m <<= 1) {
        #pragma unroll
        for (int i = 0; i < 4; ++i) {
            float od = __shfl_xor(best[i], m);
            int   oi = __shfl_xor(bidx[i], m);
            if (od < best[i] || (od == best[i] && oi < bidx[i])) {
                best[i] = od; bidx[i] = oi;
            }
        }
    }
    if (tx == 0) {
        #pragma unroll
        for (int i = 0; i < 4; ++i) outidx[rowbase + ty * 4 + i] = bidx[i];
    }
}

// ---------------- gather: one wave per row, write both halves ----------------
__global__ void gather_kernel(const float* __restrict__ C,
                              const int* __restrict__ idx,
                              float* __restrict__ out) {
    const size_t half = (size_t)N_ROWS * DIM;
    int gtid = blockIdx.x * blockDim.x + threadIdx.x;
    int lane = threadIdx.x & 63;
    int wave = gtid >> 6;
    int nwaves = (gridDim.x * blockDim.x) >> 6;
    for (int row = wave; row < N_ROWS; row += nwaves) {
        int id = idx[row];
        float4 v = reinterpret_cast<const float4*>(C + (size_t)id * DIM)[lane];
        reinterpret_cast<float4*>(out + (size_t)row * DIM)[lane] = v;
        reinterpret_cast<float4*>(out + half + (size_t)row * DIM)[lane] = v;
    }
}

extern "C" void kernel_launch(void* const* d_in, const int* in_sizes, int n_in,
                              void* d_out, int out_size, void* d_ws, size_t ws_size,
                              hipStream_t stream) {
    const float* z  = (const float*)d_in[0];   // (32,1024,256) fp32
    const float* cb = (const float*)d_in[1];   // (8192,256)    fp32
    float* out = (float*)d_out;                // 2 * 32768*256 fp32

    float* csq = (float*)d_ws;                                   // 8192 floats
    int*   idx = (int*)((char*)d_ws + N_CODES * sizeof(float));  // 32768 ints

    // 1) c_sq: 8192 waves
    csq_kernel<<<(N_CODES * 64) / 256, 256, 0, stream>>>(cb, csq);
    // 2) argmin: 512 blocks of 64 rows
    argmin_kernel<<<N_ROWS / BM, 256, 0, stream>>>(z, cb, csq, idx);
    // 3) gather both outputs
    gather_kernel<<<2048, 256, 0, stream>>>(cb, idx, out);
}